// Round 3
// baseline (970.290 us; speedup 1.0000x reference)
//
#include <hip/hip_runtime.h>
#include <hip/hip_bf16.h>

// EnhancedSpatioTemporalLayer forward, 2-kernel pipeline.
// K-AB: per (b,t): conv -> Tm (LDS) -> Z[bt][o][k*192+m] = theta^T @ Tm^T  (HBM, bf16)
// K-C : flat GEMM G[n, (bt,o)] = chebcat[n, (k,m)] @ Z[(k,m), (bt,o)] + relu + residual.

#define Bx   16
#define FINx 3
#define Nx   170
#define Tx   288
#define Hx   64
#define Ox   64
#define Kx   3
#define NP   192
#define KTOT 576            // 3 * 192
#define TMW  72             // sTm row stride (bf16)
#define NBT  (Bx * Tx)      // 4608

typedef __attribute__((ext_vector_type(8))) short bf16x8;
typedef __attribute__((ext_vector_type(4))) float f32x4;
typedef __attribute__((ext_vector_type(16))) float f32x16;

#define ZELEMS ((size_t)NBT * Ox * KTOT)          // 169,869,312
#define ZBYTES (ZELEMS * 2)                       // ~340 MB

__device__ __align__(16) __hip_bfloat16 g_chebcat[NP * KTOT]; // [n][k*192+m]
__device__ __align__(16) __hip_bfloat16 g_thetaT[NP * Hx];    // [k*64+o][c]
__device__ __align__(16) __hip_bfloat16 g_Z[ZELEMS];          // fallback Z buffer

__global__ __launch_bounds__(512)
void precompute_bf16(const float* __restrict__ cheb, const float* __restrict__ theta) {
    int idx = blockIdx.x * 512 + threadIdx.x;
    if (idx < NP * KTOT) {
        int n = idx / KTOT, kk = idx % KTOT;
        int k = kk / NP, m = kk % NP;
        float v = (n < Nx && m < Nx) ? cheb[(k * Nx + n) * Nx + m] : 0.f;
        g_chebcat[idx] = __float2bfloat16(v);
    } else if (idx < NP * KTOT + NP * Hx) {
        int j = idx - NP * KTOT;
        int c2 = j >> 6, c = j & 63;
        float v = theta[(c2 >> 6) * (Hx * Ox) + c * Ox + (c2 & 63)];
        g_thetaT[j] = __float2bfloat16(v);
    }
}

// ---------------- Kernel AB: conv + theta GEMM -> Z ----------------
__global__ __launch_bounds__(256, 4)
void stgcn_conv_theta(const float* __restrict__ x,
                      const float* __restrict__ conv_w,
                      const float* __restrict__ conv_b,
                      __hip_bfloat16* __restrict__ Z) {
    __shared__ __align__(16) __hip_bfloat16 sTm[NP * TMW];  // 27.6 KB
    __shared__ float sXs[Nx * 9];                           // 6.1 KB

    const int tid = threadIdx.x;
    const int vid = (blockIdx.x & 7) * 576 + (blockIdx.x >> 3);  // XCD chunking
    const int b  = vid / Tx;
    const int t0 = vid % Tx;

    for (int idx = tid; idx < Nx * 9; idx += 256) {
        int n = idx / 9, r = idx % 9, f = r / 3, j = r % 3;
        int tt = t0 - 1 + j;
        float v = 0.f;
        if (tt >= 0 && tt < Tx) v = x[((b * FINx + f) * Nx + n) * Tx + tt];
        sXs[idx] = v;
    }
    const int cc = tid & 63;
    float wreg[9];
#pragma unroll
    for (int r = 0; r < 9; ++r) wreg[r] = conv_w[cc * 9 + r];
    const float bias = conv_b[cc];
    __syncthreads();

    for (int m = (tid >> 6); m < Nx; m += 4) {
        float acc = bias;
#pragma unroll
        for (int r = 0; r < 9; ++r) acc += sXs[m * 9 + r] * wreg[r];
        sTm[m * TMW + cc] = __float2bfloat16(fmaxf(acc, 0.f));
    }
    for (int idx = tid; idx < (NP - Nx) * 64; idx += 256) {
        int m = Nx + idx / 64, c = idx % 64;
        sTm[m * TMW + c] = __float2bfloat16(0.f);
    }
    __syncthreads();

    const int lane = tid & 63;
    const int w    = tid >> 6;
    const int l16  = lane & 15;
    const int lk   = lane >> 4;
    __hip_bfloat16* zbase = Z + (size_t)vid * (Ox * KTOT);

#pragma unroll
    for (int a3 = 0; a3 < 3; ++a3) {
        const int a = w * 3 + a3;          // m-tile 0..11
        f32x4 acc[12];
#pragma unroll
        for (int t = 0; t < 12; ++t) acc[t] = (f32x4)0.f;

#pragma unroll
        for (int s = 0; s < 2; ++s) {
            bf16x8 bfr = *(const bf16x8*)(&sTm[(a * 16 + l16) * TMW + s * 32 + lk * 8]);
#pragma unroll
            for (int t = 0; t < 12; ++t) {
                bf16x8 afr = *(const bf16x8*)(&g_thetaT[(t * 16 + l16) * Hx + s * 32 + lk * 8]);
                acc[t] = __builtin_amdgcn_mfma_f32_16x16x32_bf16(afr, bfr, acc[t], 0, 0, 0);
            }
        }
        // store D[c2][m]: lane holds m = a*16+l16 (fixed), c2 = t*16 + lk*4 + r
#pragma unroll
        for (int t = 0; t < 12; ++t) {
            const int k = t >> 2;
#pragma unroll
            for (int r = 0; r < 4; ++r) {
                int c2 = t * 16 + lk * 4 + r;
                int o  = c2 & 63;
                zbase[(size_t)o * KTOT + k * NP + a * 16 + l16] = __float2bfloat16(acc[t][r]);
            }
        }
    }
}

// ---------------- Kernel C: flat cheb GEMM + epilogue ----------------
__global__ __launch_bounds__(512, 4)
void stgcn_cheb(const __hip_bfloat16* __restrict__ Z,
                const float* __restrict__ x,
                const float* __restrict__ res_w,
                const float* __restrict__ res_b,
                float* __restrict__ out) {
    __shared__ float sXt[2][FINx][NP];   // 4.6 KB (n padded to 192)
    __shared__ float sResW[Ox * 3];
    __shared__ float sResB[Ox];

    const int tid = threadIdx.x;
    const int vid = (blockIdx.x & 7) * 288 + (blockIdx.x >> 3);  // 2304 = 8*288
    const int bt0 = vid * 2;

    for (int idx = tid; idx < 2 * FINx * NP; idx += 512) {
        int bti = idx / (FINx * NP);
        int rem = idx % (FINx * NP);
        int f = rem / NP, n = rem % NP;
        int bt = bt0 + bti, b = bt / Tx, t = bt % Tx;
        float v = 0.f;
        if (n < Nx) v = x[((b * FINx + f) * Nx + n) * Tx + t];
        sXt[bti][f][n] = v;
    }
    for (int idx = tid; idx < Ox * 3; idx += 512) sResW[idx] = res_w[idx];
    for (int idx = tid; idx < Ox;     idx += 512) sResB[idx] = res_b[idx];
    __syncthreads();

    const int lane = tid & 63;
    const int w    = tid >> 6;
    const int rh   = w & 1;        // row half: n-base rh*96
    const int colq = w >> 1;       // col quarter: 32 cols
    const int l31  = lane & 31;
    const int hi   = lane >> 5;
    const int bti  = colq >> 1;
    const int obase = (colq & 1) * 32;
    const int bt   = bt0 + bti;

    const __hip_bfloat16* zrow = Z + ((size_t)bt * Ox + obase + l31) * KTOT + hi * 8;
    const __hip_bfloat16* arow = g_chebcat + (size_t)(rh * 96 + l31) * KTOT + hi * 8;

    f32x16 acc[3];
#pragma unroll
    for (int rt = 0; rt < 3; ++rt) acc[rt] = (f32x16)0.f;

#pragma unroll 4
    for (int s = 0; s < 36; ++s) {
        bf16x8 bfr = *(const bf16x8*)(zrow + s * 16);
#pragma unroll
        for (int rt = 0; rt < 3; ++rt) {
            bf16x8 afr = *(const bf16x8*)(arow + (size_t)rt * 32 * KTOT + s * 16);
            acc[rt] = __builtin_amdgcn_mfma_f32_32x32x16_bf16(afr, bfr, acc[rt], 0, 0, 0);
        }
    }

    // epilogue: C-frag 32x32: col o = obase+l31, row n = rh*96 + rt*32 + (reg&3)+8*(reg>>2)+4*hi
    const int b = bt / Tx, t = bt % Tx;
    const int o = obase + l31;
    const float rw0 = sResW[o * 3 + 0], rw1 = sResW[o * 3 + 1], rw2 = sResW[o * 3 + 2];
    const float rb  = sResB[o];
    float* op = out + ((size_t)(b * Ox + o) * Nx) * Tx + t;
#pragma unroll
    for (int rt = 0; rt < 3; ++rt) {
#pragma unroll
        for (int reg = 0; reg < 16; ++reg) {
            int n = rh * 96 + rt * 32 + (reg & 3) + 8 * (reg >> 2) + 4 * hi;
            if (n < Nx) {
                float resv = rb + sXt[bti][0][n] * rw0 + sXt[bti][1][n] * rw1
                                + sXt[bti][2][n] * rw2;
                op[n * Tx] = fmaxf(acc[rt][reg], 0.f) + resv;
            }
        }
    }
}

extern "C" void kernel_launch(void* const* d_in, const int* in_sizes, int n_in,
                              void* d_out, int out_size, void* d_ws, size_t ws_size,
                              hipStream_t stream) {
    const float* x      = (const float*)d_in[0];
    const float* cheb   = (const float*)d_in[2];
    const float* conv_w = (const float*)d_in[3];
    const float* conv_b = (const float*)d_in[4];
    const float* theta  = (const float*)d_in[5];
    const float* res_w  = (const float*)d_in[6];
    const float* res_b  = (const float*)d_in[7];
    float* out = (float*)d_out;

    __hip_bfloat16* zptr;
    if (ws_size >= ZBYTES) {
        zptr = (__hip_bfloat16*)d_ws;
    } else {
        void* sym = nullptr;
        hipGetSymbolAddress(&sym, HIP_SYMBOL(g_Z));
        zptr = (__hip_bfloat16*)sym;
    }

    int pre_elems = NP * KTOT + NP * Hx;
    hipLaunchKernelGGL(precompute_bf16, dim3((pre_elems + 511) / 512), dim3(512), 0, stream,
                       cheb, theta);
    hipLaunchKernelGGL(stgcn_conv_theta, dim3(NBT), dim3(256), 0, stream,
                       x, conv_w, conv_b, zptr);
    hipLaunchKernelGGL(stgcn_cheb, dim3(NBT / 2), dim3(512), 0, stream,
                       zptr, x, res_w, res_b, out);
}

// Round 4
// 456.852 us; speedup vs baseline: 2.1239x; 2.1239x over previous
//
#include <hip/hip_runtime.h>
#include <hip/hip_bf16.h>

// EnhancedSpatioTemporalLayer fused forward, round 4.
// One block per (b,t), 512 thr, 2 blocks/CU (59 KB LDS, <=128 VGPR).
// conv(f32) -> per k: [small GEMM Z_k = Tm@theta_k -> sZk -> big GEMM
// GT += sZk @ chebcat_k] -> relu + residual -> out.
// theta/cheb B/A-frags stream from L2-resident precomputed bf16 arrays.

#define Bx   16
#define FINx 3
#define Nx   170
#define Tx   288
#define Hx   64
#define Ox   64
#define Kx   3
#define NP   192            // padded n/m (12 x 16)
#define KTOT 576            // 3 * 192
#define TMW  72             // sTm row stride (bf16): 144B -> 2-way banks
#define ZW   200            // sZk row stride (bf16): 400B -> 2-way banks
#define NBT  (Bx * Tx)      // 4608

typedef __attribute__((ext_vector_type(8))) short bf16x8;
typedef __attribute__((ext_vector_type(4))) short bf16x4;
typedef __attribute__((ext_vector_type(4))) float f32x4;

__device__ __align__(16) __hip_bfloat16 g_chebcat[NP * KTOT]; // [n][k*192+m] = cheb_k[n][m]
__device__ __align__(16) __hip_bfloat16 g_thetaT[NP * Hx];    // [k*64+o][c] = theta[k][c][o]

static __device__ __forceinline__ short f2bf(float f) {
    __hip_bfloat16 h = __float2bfloat16(f);
    return *reinterpret_cast<short*>(&h);
}

__global__ __launch_bounds__(512)
void precompute_bf16(const float* __restrict__ cheb, const float* __restrict__ theta) {
    int idx = blockIdx.x * 512 + threadIdx.x;
    if (idx < NP * KTOT) {
        int n = idx / KTOT, kk = idx % KTOT;
        int k = kk / NP, m = kk % NP;
        float v = (n < Nx && m < Nx) ? cheb[(k * Nx + n) * Nx + m] : 0.f;  // symmetric
        g_chebcat[idx] = __float2bfloat16(v);
    } else if (idx < NP * KTOT + NP * Hx) {
        int j = idx - NP * KTOT;
        int c2 = j >> 6, c = j & 63;
        float v = theta[(c2 >> 6) * (Hx * Ox) + c * Ox + (c2 & 63)];
        g_thetaT[j] = __float2bfloat16(v);
    }
}

__global__ __launch_bounds__(512, 4)
void stgcn_fused2(const float* __restrict__ x,
                  const float* __restrict__ conv_w,
                  const float* __restrict__ conv_b,
                  const float* __restrict__ res_w,
                  const float* __restrict__ res_b,
                  float* __restrict__ out) {
    __shared__ __align__(16) __hip_bfloat16 sTm[NP * TMW];  // 27.6 KB
    __shared__ __align__(16) __hip_bfloat16 sZk[Ox * ZW];   // 25.6 KB
    __shared__ float sXs[Nx * 9];                           // 6.1 KB
    __shared__ float sResW[Ox * 3];
    __shared__ float sResB[Ox];

    const int tid = threadIdx.x;
    const int vid = (blockIdx.x & 7) * 576 + (blockIdx.x >> 3);  // XCD-chunked swizzle
    const int b  = vid / Tx;
    const int t0 = vid % Tx;

    // ---- stage x slice + residual params ----
    for (int idx = tid; idx < Nx * 9; idx += 512) {
        int n = idx / 9, r = idx % 9, f = r / 3, j = r % 3;
        int tt = t0 - 1 + j;
        float v = 0.f;
        if (tt >= 0 && tt < Tx) v = x[((b * FINx + f) * Nx + n) * Tx + tt];
        sXs[idx] = v;
    }
    for (int idx = tid; idx < Ox * 3; idx += 512) sResW[idx] = res_w[idx];
    for (int idx = tid; idx < Ox;     idx += 512) sResB[idx] = res_b[idx];

    const int cc = tid & 63;
    float wreg[9];
#pragma unroll
    for (int r = 0; r < 9; ++r) wreg[r] = conv_w[cc * 9 + r];
    const float bias = conv_b[cc];

    __syncthreads();

    // ---- temporal conv + ReLU -> bf16 sTm[m][cc]; zero pad rows ----
    for (int m = (tid >> 6); m < Nx; m += 8) {
        float acc = bias;
#pragma unroll
        for (int r = 0; r < 9; ++r) acc += sXs[m * 9 + r] * wreg[r];
        sTm[m * TMW + cc] = __float2bfloat16(fmaxf(acc, 0.f));
    }
    for (int idx = tid; idx < (NP - Nx) * 64; idx += 512) {
        int m = Nx + idx / 64, c = idx % 64;
        sTm[m * TMW + c] = __float2bfloat16(0.f);
    }

    const int lane = tid & 63;
    const int w    = tid >> 6;
    const int l16  = lane & 15;
    const int lk   = lane >> 4;

    const int mg = w & 3;        // small GEMM: m-tiles mg*3+j  (j=0..2)
    const int og = w >> 2;       // small GEMM: o-tiles og*2+u  (u=0..1)
    const int wr = w & 1;        // big GEMM:   o-tiles wr*2+oi (oi=0..1)
    const int wc = w >> 1;       // big GEMM:   n-tiles wc*3+nj (nj=0..2)

    f32x4 accb[2][3];            // persistent GT accumulator
#pragma unroll
    for (int oi = 0; oi < 2; ++oi)
#pragma unroll
        for (int nj = 0; nj < 3; ++nj) accb[oi][nj] = (f32x4)0.f;

    for (int k = 0; k < Kx; ++k) {
        __syncthreads();   // k=0: conv done; k>0: big GEMM done reading sZk

        // ---- small GEMM: Z_k[m][o] = Tm[192x64] @ theta_k[64x64] ----
        f32x4 accs[3][2];
#pragma unroll
        for (int j = 0; j < 3; ++j)
#pragma unroll
            for (int u = 0; u < 2; ++u) accs[j][u] = (f32x4)0.f;

#pragma unroll
        for (int s = 0; s < 2; ++s) {
            bf16x8 afr[3], bfr[2];
#pragma unroll
            for (int j = 0; j < 3; ++j)
                afr[j] = *(const bf16x8*)((const char*)sTm +
                         ((mg * 3 + j) * 16 + l16) * (TMW * 2) + s * 64 + lk * 16);
#pragma unroll
            for (int u = 0; u < 2; ++u)
                bfr[u] = *(const bf16x8*)((const char*)g_thetaT +
                         (k * 64 + (og * 2 + u) * 16 + l16) * 128 + s * 64 + lk * 16);
#pragma unroll
            for (int j = 0; j < 3; ++j)
#pragma unroll
                for (int u = 0; u < 2; ++u)
                    accs[j][u] = __builtin_amdgcn_mfma_f32_16x16x32_bf16(afr[j], bfr[u], accs[j][u], 0, 0, 0);
        }
        // store transposed slice: sZk[o][m]  (D: col o = tile+l16, rows m = lk*4+r)
#pragma unroll
        for (int j = 0; j < 3; ++j)
#pragma unroll
            for (int u = 0; u < 2; ++u) {
                int o  = (og * 2 + u) * 16 + l16;
                int m0 = (mg * 3 + j) * 16 + lk * 4;
                bf16x4 v;
#pragma unroll
                for (int r = 0; r < 4; ++r) v[r] = f2bf(accs[j][u][r]);
                *(bf16x4*)((char*)sZk + o * (ZW * 2) + m0 * 2) = v;
            }
        __syncthreads();

        // ---- big GEMM partial: GT[o][n] += Z_k^T[o][m] @ cheb_k[n][m]-frags ----
#pragma unroll
        for (int s = 0; s < 6; ++s) {
            bf16x8 afr2[2], bfr2[3];
#pragma unroll
            for (int oi = 0; oi < 2; ++oi)
                afr2[oi] = *(const bf16x8*)((const char*)sZk +
                           ((wr * 2 + oi) * 16 + l16) * (ZW * 2) + s * 64 + lk * 16);
#pragma unroll
            for (int nj = 0; nj < 3; ++nj)
                bfr2[nj] = *(const bf16x8*)((const char*)g_chebcat +
                           ((wc * 3 + nj) * 16 + l16) * (KTOT * 2) + k * (NP * 2) + s * 64 + lk * 16);
#pragma unroll
            for (int oi = 0; oi < 2; ++oi)
#pragma unroll
                for (int nj = 0; nj < 3; ++nj)
                    accb[oi][nj] = __builtin_amdgcn_mfma_f32_16x16x32_bf16(afr2[oi], bfr2[nj], accb[oi][nj], 0, 0, 0);
        }
    }

    // ---- epilogue: relu + residual, scatter store ----
#pragma unroll
    for (int nj = 0; nj < 3; ++nj) {
        int n = (wc * 3 + nj) * 16 + l16;
        if (n < Nx) {
            float xf0 = sXs[n * 9 + 1];
            float xf1 = sXs[n * 9 + 4];
            float xf2 = sXs[n * 9 + 7];
#pragma unroll
            for (int oi = 0; oi < 2; ++oi) {
#pragma unroll
                for (int r = 0; r < 4; ++r) {
                    int o = (wr * 2 + oi) * 16 + lk * 4 + r;
                    float resv = sResB[o] + xf0 * sResW[o * 3 + 0]
                                          + xf1 * sResW[o * 3 + 1]
                                          + xf2 * sResW[o * 3 + 2];
                    out[((b * Ox + o) * Nx + n) * Tx + t0] =
                        fmaxf(accb[oi][nj][r], 0.f) + resv;
                }
            }
        }
    }
}

extern "C" void kernel_launch(void* const* d_in, const int* in_sizes, int n_in,
                              void* d_out, int out_size, void* d_ws, size_t ws_size,
                              hipStream_t stream) {
    const float* x      = (const float*)d_in[0];
    const float* cheb   = (const float*)d_in[2];
    const float* conv_w = (const float*)d_in[3];
    const float* conv_b = (const float*)d_in[4];
    const float* theta  = (const float*)d_in[5];
    const float* res_w  = (const float*)d_in[6];
    const float* res_b  = (const float*)d_in[7];
    float* out = (float*)d_out;

    int pre_elems = NP * KTOT + NP * Hx;
    hipLaunchKernelGGL(precompute_bf16, dim3((pre_elems + 511) / 512), dim3(512), 0, stream,
                       cheb, theta);
    hipLaunchKernelGGL(stgcn_fused2, dim3(NBT), dim3(512), 0, stream,
                       x, conv_w, conv_b, res_w, res_b, out);
}

// Round 5
// 304.952 us; speedup vs baseline: 3.1818x; 1.4981x over previous
//
#include <hip/hip_runtime.h>
#include <hip/hip_bf16.h>

// EnhancedSpatioTemporalLayer fused forward, round 5.
// Round-4 structure (per-(b,t) block, 512 thr, 2 blocks/CU) with cheb/theta
// stored in FRAGMENT-ORDER global layouts: each wave's MFMA B-frag load is
// base + lane*16 (coalesced 1KB), replacing 64-line gathers (round-4 limiter).

#define Bx   16
#define FINx 3
#define Nx   170
#define Tx   288
#define Hx   64
#define Ox   64
#define Kx   3
#define NP   192            // padded n/m (12 x 16)
#define TMW  72             // sTm row stride (bf16): 144B -> 2-way banks
#define ZW   200            // sZk row stride (bf16): 400B -> 2-way banks
#define NBT  (Bx * Tx)      // 4608

#define CHEBF_ELEMS (Kx * 6 * 12 * 64 * 8)   // 110592: [k][s][nt][lane][8]
#define THF_ELEMS   (Kx * 2 * 4 * 64 * 8)    // 12288:  [k][s][ot][lane][8]

typedef __attribute__((ext_vector_type(8))) short bf16x8;
typedef __attribute__((ext_vector_type(4))) short bf16x4;
typedef __attribute__((ext_vector_type(4))) float f32x4;

__device__ __align__(16) __hip_bfloat16 g_chebfrag[CHEBF_ELEMS];
__device__ __align__(16) __hip_bfloat16 g_thfrag[THF_ELEMS];

static __device__ __forceinline__ short f2bf(float f) {
    __hip_bfloat16 h = __float2bfloat16(f);
    return *reinterpret_cast<short*>(&h);
}

// frag-order semantics (matches the 16x16x32 A/B mapping used since round 2):
//   g_chebfrag[(((k*6+s)*12+nt)*64+lane)*8+j] = cheb_k[n][m],
//       n = nt*16 + (lane&15), m = s*32 + (lane>>4)*8 + j   (0 if n,m >= 170)
//   g_thfrag [(((k*2+s)*4+ot)*64+lane)*8+j]  = theta[k][c][o],
//       o = ot*16 + (lane&15), c = s*32 + (lane>>4)*8 + j
__global__ __launch_bounds__(512)
void precompute_frag(const float* __restrict__ cheb, const float* __restrict__ theta) {
    int idx = blockIdx.x * 512 + threadIdx.x;
    if (idx < CHEBF_ELEMS) {
        int j = idx & 7, lane = (idx >> 3) & 63, rest = idx >> 9;
        int nt = rest % 12; rest /= 12;
        int s = rest % 6, k = rest / 6;
        int n = nt * 16 + (lane & 15);
        int m = s * 32 + (lane >> 4) * 8 + j;
        float v = (n < Nx && m < Nx) ? cheb[(k * Nx + n) * Nx + m] : 0.f;
        g_chebfrag[idx] = __float2bfloat16(v);
    } else if (idx < CHEBF_ELEMS + THF_ELEMS) {
        int jdx = idx - CHEBF_ELEMS;
        int j = jdx & 7, lane = (jdx >> 3) & 63, rest = jdx >> 9;
        int ot = rest % 4; rest /= 4;
        int s = rest % 2, k = rest / 2;
        int o = ot * 16 + (lane & 15);
        int c = s * 32 + (lane >> 4) * 8 + j;
        g_thfrag[jdx] = __float2bfloat16(theta[(k * Hx + c) * Ox + o]);
    }
}

__global__ __launch_bounds__(512, 4)
void stgcn_fused3(const float* __restrict__ x,
                  const float* __restrict__ conv_w,
                  const float* __restrict__ conv_b,
                  const float* __restrict__ res_w,
                  const float* __restrict__ res_b,
                  float* __restrict__ out) {
    __shared__ __align__(16) __hip_bfloat16 sTm[NP * TMW];  // 27.6 KB
    __shared__ __align__(16) __hip_bfloat16 sZk[Ox * ZW];   // 25.6 KB
    __shared__ float sXs[Nx * 9];                           // 6.1 KB
    __shared__ float sResW[Ox * 3];
    __shared__ float sResB[Ox];

    const int tid = threadIdx.x;
    const int vid = (blockIdx.x & 7) * 576 + (blockIdx.x >> 3);  // XCD-chunked swizzle
    const int b  = vid / Tx;
    const int t0 = vid % Tx;

    // ---- stage x slice + residual params ----
    for (int idx = tid; idx < Nx * 9; idx += 512) {
        int n = idx / 9, r = idx % 9, f = r / 3, j = r % 3;
        int tt = t0 - 1 + j;
        float v = 0.f;
        if (tt >= 0 && tt < Tx) v = x[((b * FINx + f) * Nx + n) * Tx + tt];
        sXs[idx] = v;
    }
    for (int idx = tid; idx < Ox * 3; idx += 512) sResW[idx] = res_w[idx];
    for (int idx = tid; idx < Ox;     idx += 512) sResB[idx] = res_b[idx];

    const int cc = tid & 63;
    float wreg[9];
#pragma unroll
    for (int r = 0; r < 9; ++r) wreg[r] = conv_w[cc * 9 + r];
    const float bias = conv_b[cc];

    __syncthreads();

    // ---- temporal conv + ReLU -> bf16 sTm[m][cc]; zero pad rows ----
    for (int m = (tid >> 6); m < Nx; m += 8) {
        float acc = bias;
#pragma unroll
        for (int r = 0; r < 9; ++r) acc += sXs[m * 9 + r] * wreg[r];
        sTm[m * TMW + cc] = __float2bfloat16(fmaxf(acc, 0.f));
    }
    for (int idx = tid; idx < (NP - Nx) * 64; idx += 512) {
        int m = Nx + idx / 64, c = idx % 64;
        sTm[m * TMW + c] = __float2bfloat16(0.f);
    }

    const int lane = tid & 63;
    const int w    = tid >> 6;
    const int l16  = lane & 15;
    const int lk   = lane >> 4;

    const int mg = w & 3;        // small GEMM: m-tiles mg*3+j  (j=0..2)
    const int og = w >> 2;       // small GEMM: o-tiles og*2+u  (u=0..1)
    const int wr = w & 1;        // big GEMM:   o-tiles wr*2+oi (oi=0..1)
    const int wc = w >> 1;       // big GEMM:   n-tiles wc*3+nj (nj=0..2)

    f32x4 accb[2][3];            // persistent GT accumulator
#pragma unroll
    for (int oi = 0; oi < 2; ++oi)
#pragma unroll
        for (int nj = 0; nj < 3; ++nj) accb[oi][nj] = (f32x4)0.f;

    for (int k = 0; k < Kx; ++k) {
        __syncthreads();   // k=0: conv done; k>0: big GEMM done reading sZk

        // ---- small GEMM: Z_k[m][o] = Tm[192x64] @ theta_k[64x64] ----
        f32x4 accs[3][2];
#pragma unroll
        for (int j = 0; j < 3; ++j)
#pragma unroll
            for (int u = 0; u < 2; ++u) accs[j][u] = (f32x4)0.f;

#pragma unroll
        for (int s = 0; s < 2; ++s) {
            bf16x8 afr[3], bfr[2];
#pragma unroll
            for (int j = 0; j < 3; ++j)
                afr[j] = *(const bf16x8*)((const char*)sTm +
                         ((mg * 3 + j) * 16 + l16) * (TMW * 2) + s * 64 + lk * 16);
#pragma unroll
            for (int u = 0; u < 2; ++u)
                bfr[u] = *(const bf16x8*)(&g_thfrag[
                         ((((k * 2 + s) * 4) + og * 2 + u) * 64 + lane) * 8]);
#pragma unroll
            for (int j = 0; j < 3; ++j)
#pragma unroll
                for (int u = 0; u < 2; ++u)
                    accs[j][u] = __builtin_amdgcn_mfma_f32_16x16x32_bf16(afr[j], bfr[u], accs[j][u], 0, 0, 0);
        }
        // store transposed slice: sZk[o][m]  (D: col o = tile+l16, rows m = lk*4+r)
#pragma unroll
        for (int j = 0; j < 3; ++j)
#pragma unroll
            for (int u = 0; u < 2; ++u) {
                int o  = (og * 2 + u) * 16 + l16;
                int m0 = (mg * 3 + j) * 16 + lk * 4;
                bf16x4 v;
#pragma unroll
                for (int r = 0; r < 4; ++r) v[r] = f2bf(accs[j][u][r]);
                *(bf16x4*)((char*)sZk + o * (ZW * 2) + m0 * 2) = v;
            }
        __syncthreads();

        // ---- big GEMM partial: GT[o][n] += Z_k^T[o][m] @ cheb_k[n][m]-frags ----
#pragma unroll
        for (int s = 0; s < 6; ++s) {
            bf16x8 afr2[2], bfr2[3];
#pragma unroll
            for (int oi = 0; oi < 2; ++oi)
                afr2[oi] = *(const bf16x8*)((const char*)sZk +
                           ((wr * 2 + oi) * 16 + l16) * (ZW * 2) + s * 64 + lk * 16);
#pragma unroll
            for (int nj = 0; nj < 3; ++nj)
                bfr2[nj] = *(const bf16x8*)(&g_chebfrag[
                           ((((k * 6 + s) * 12) + wc * 3 + nj) * 64 + lane) * 8]);
#pragma unroll
            for (int oi = 0; oi < 2; ++oi)
#pragma unroll
                for (int nj = 0; nj < 3; ++nj)
                    accb[oi][nj] = __builtin_amdgcn_mfma_f32_16x16x32_bf16(afr2[oi], bfr2[nj], accb[oi][nj], 0, 0, 0);
        }
    }

    // ---- epilogue: relu + residual, scatter store ----
#pragma unroll
    for (int nj = 0; nj < 3; ++nj) {
        int n = (wc * 3 + nj) * 16 + l16;
        if (n < Nx) {
            float xf0 = sXs[n * 9 + 1];
            float xf1 = sXs[n * 9 + 4];
            float xf2 = sXs[n * 9 + 7];
#pragma unroll
            for (int oi = 0; oi < 2; ++oi) {
#pragma unroll
                for (int r = 0; r < 4; ++r) {
                    int o = (wr * 2 + oi) * 16 + lk * 4 + r;
                    float resv = sResB[o] + xf0 * sResW[o * 3 + 0]
                                          + xf1 * sResW[o * 3 + 1]
                                          + xf2 * sResW[o * 3 + 2];
                    out[((b * Ox + o) * Nx + n) * Tx + t0] =
                        fmaxf(accb[oi][nj][r], 0.f) + resv;
                }
            }
        }
    }
}

extern "C" void kernel_launch(void* const* d_in, const int* in_sizes, int n_in,
                              void* d_out, int out_size, void* d_ws, size_t ws_size,
                              hipStream_t stream) {
    const float* x      = (const float*)d_in[0];
    const float* cheb   = (const float*)d_in[2];
    const float* conv_w = (const float*)d_in[3];
    const float* conv_b = (const float*)d_in[4];
    const float* theta  = (const float*)d_in[5];
    const float* res_w  = (const float*)d_in[6];
    const float* res_b  = (const float*)d_in[7];
    float* out = (float*)d_out;

    int pre_elems = CHEBF_ELEMS + THF_ELEMS;
    hipLaunchKernelGGL(precompute_frag, dim3((pre_elems + 511) / 512), dim3(512), 0, stream,
                       cheb, theta);
    hipLaunchKernelGGL(stgcn_fused3, dim3(NBT), dim3(512), 0, stream,
                       x, conv_w, conv_b, res_w, res_b, out);
}